// Round 4
// baseline (297.653 us; speedup 1.0000x reference)
//
#include <hip/hip_runtime.h>

#define CUTOFF 5.0f
#define GAMMA 40.96f              // (32/5)^2
#define MU_STEP 0.16129032f       // 5/31
#define INV_MU 6.2f               // 31/5
#define PI_F 3.14159265358979f
#define MAXDEG 24                 // filtered degree ~Poisson(4.42); P(any node >=24) ~ 3e-6

// ---------------------------------------------------------------------------
// R13: R11 structure (16 thr/node, 16 nodes/block -- VGPR 60, best occupancy)
// but ALL per-edge transcendental/cross-lane work moved to fill:
//  * fill appends a compact 48B record {v*env, kl, e0..e6} per surviving edge
//    (global atomic counter); bucket stores {src, cidx}.
//  * gather: w = sum_j e_j * Wrbf[kl+j, c] -- 7 FMA, NO shfl, NO exp, NO
//    clamp. Compact load is independent of the h chain, so h latency hides
//    under the w math. Odd tail handled outside the 2-edge loop (removes
//    per-iter i1ok selects).
// R12 lesson: VGPR cliff at 64/128 -- keep gather regs < 128 (target ~90).
// ws: cmp float4[3*cap] | rec2 int2[N*24] (9.6MB) | deg[N] | cnt[1].
//     cap from ws_size; expected use ~221k recs = 10.6MB (cap ~1.4x margin).
// ---------------------------------------------------------------------------

__global__ __launch_bounds__(256) void k_fill_geom(
    const float* __restrict__ pos, const int* __restrict__ ei,
    int* __restrict__ deg, int* __restrict__ cnt,
    int2* __restrict__ rec2, float4* __restrict__ cmp, int cap, int E)
{
    int e = blockIdx.x * 256 + threadIdx.x;
    if (e >= E) return;
    int src = ei[e], dst = ei[E + e];
    float dx = pos[dst*3+0] - pos[src*3+0];
    float dy = pos[dst*3+1] - pos[src*3+1];
    float dz = pos[dst*3+2] - pos[src*3+2];
    float d = sqrtf(dx*dx + dy*dy + dz*dz + 1e-12f);
    if (d < CUTOFF) {
        int slot = atomicAdd(&deg[dst], 1);
        if (slot < MAXDEG) {                    // guard: never taken in practice
            int ci = atomicAdd(cnt, 1) + 1;     // record 0 reserved for overflow
            if (ci >= cap) {                    // never taken in practice
                cmp[0] = make_float4(0,0,0,0);  // zero record: edge contributes 0,
                cmp[1] = make_float4(0,0,0,0);  // same semantics as dropped edge
                cmp[2] = make_float4(0,0,0,0);
                ci = 0;
            }
            // v = (rel/d) * env(d); env folds linearly into the grade-1 mv
            const float s = (0.5f * (__cosf(PI_F * d * (1.0f/CUTOFF)) + 1.0f)) / d;
            // 7-term RBF window, clamped so kl+6 <= 31 (identical to R11 math)
            const int kl = min(max(0, __float2int_rn(d * INV_MU) - 3), 25);
            float ex[7];
            #pragma unroll
            for (int j = 0; j < 7; ++j) {
                const float x = d - MU_STEP * (float)(kl + j);
                ex[j] = __expf(-GAMMA * x * x);
            }
            cmp[3*ci+0] = make_float4(dx*s, dy*s, dz*s, (float)kl);
            cmp[3*ci+1] = make_float4(ex[0], ex[1], ex[2], ex[3]);
            cmp[3*ci+2] = make_float4(ex[4], ex[5], ex[6], 0.0f);
            rec2[dst*MAXDEG + slot] = make_int2(src, ci);
        }
    }
}

// gp(a, v), v grade-1 (= unit rel * env), scaled by w, accumulated.
// blades: 0:1 1:e1 2:e2 3:e3 4:e12 5:e13 6:e23 7:e123
__device__ __forceinline__ void gp_acc(
    const float4& A, const float4& B, const float4& g, float w,
    float& m0, float& m1, float& m2, float& m3,
    float& m4, float& m5, float& m6, float& m7)
{
    m0 += (A.y*g.x + A.z*g.y + A.w*g.z) * w;
    m1 += (A.x*g.x + B.x*g.y + B.y*g.z) * w;
    m2 += (A.x*g.y - B.x*g.x + B.z*g.z) * w;
    m3 += (A.x*g.z - B.y*g.x - B.z*g.y) * w;
    m4 += (A.y*g.y - A.z*g.x + B.w*g.z) * w;
    m5 += (A.y*g.z - A.w*g.x - B.w*g.y) * w;
    m6 += (A.z*g.z - A.w*g.y + B.w*g.x) * w;
    m7 += (B.z*g.x - B.y*g.y + B.x*g.z) * w;
}

__global__ __launch_bounds__(256) void k_gather_finalize(
    const float* __restrict__ h,
    const int2* __restrict__ rec2, const int* __restrict__ deg,
    const float4* __restrict__ cmp,
    const float* __restrict__ Wrbf, const float* __restrict__ Wout,
    const float* __restrict__ Wsgp, float* __restrict__ out, int N)
{
    __shared__ float s_wr[512];        // W_rbf [32,16]
    __shared__ float s_Wout[256];
    __shared__ float s_Wsgp[256];
    __shared__ float s_agg[16*132];
    __shared__ float s_h[16*132];

    const int t  = threadIdx.x;
    const int nl = t >> 4;
    const int c  = t & 15;
    const long long nodeBase = (long long)blockIdx.x * 16;
    const long long n = nodeBase + nl;

    s_wr[t]       = Wrbf[t];
    s_wr[t + 256] = Wrbf[t + 256];
    s_Wout[t] = Wout[t];
    s_Wsgp[t] = Wsgp[t];

    for (int idx = t; idx < 512; idx += 256) {
        int nn = idx >> 5;
        int r  = idx & 31;
        long long node = nodeBase + nn;
        float4 vh = make_float4(0,0,0,0);
        if (node < N) vh = *(const float4*)(h + node*128 + (long long)r*4);
        *(float4*)(&s_h[nn*132 + r*4]) = vh;
    }
    __syncthreads();

    float m0=0,m1=0,m2=0,m3=0,m4=0,m5=0,m6=0,m7=0;
    if (n < N) {
        const int start = (int)n * MAXDEG;
        const int dg    = min(deg[n], MAXDEG);
        int base = 0;
        for (; base + 1 < dg; base += 2) {
            const int4 rr = *(const int4*)(rec2 + start + base);   // {s0,ci0,s1,ci1}

            // h loads first: 2 independent 32B chains in flight during w math
            const float4* hp0 = (const float4*)(h) + (((long long)rr.x) << 5) + (c << 1);
            const float4* hp1 = (const float4*)(h) + (((long long)rr.z) << 5) + (c << 1);
            const float4 A0 = hp0[0], B0 = hp0[1];
            const float4 A1 = hp1[0], B1 = hp1[1];

            const float4 g0  = cmp[3*rr.y],   g1  = cmp[3*rr.w];
            const float4 E0a = cmp[3*rr.y+1], E1a = cmp[3*rr.w+1];
            const float4 E0b = cmp[3*rr.y+2], E1b = cmp[3*rr.w+2];

            const float* wr0 = s_wr + ((int)g0.w)*16 + c;
            const float* wr1 = s_wr + ((int)g1.w)*16 + c;
            const float w0 = E0a.x*wr0[0]  + E0a.y*wr0[16] + E0a.z*wr0[32] + E0a.w*wr0[48]
                           + E0b.x*wr0[64] + E0b.y*wr0[80] + E0b.z*wr0[96];
            const float w1 = E1a.x*wr1[0]  + E1a.y*wr1[16] + E1a.z*wr1[32] + E1a.w*wr1[48]
                           + E1b.x*wr1[64] + E1b.y*wr1[80] + E1b.z*wr1[96];

            gp_acc(A0, B0, g0, w0, m0,m1,m2,m3,m4,m5,m6,m7);
            gp_acc(A1, B1, g1, w1, m0,m1,m2,m3,m4,m5,m6,m7);
        }
        if (base < dg) {                       // odd tail: single edge
            const int2 rr = rec2[start + base];
            const float4* hp0 = (const float4*)(h) + (((long long)rr.x) << 5) + (c << 1);
            const float4 A0 = hp0[0], B0 = hp0[1];
            const float4 g0  = cmp[3*rr.y];
            const float4 E0a = cmp[3*rr.y+1];
            const float4 E0b = cmp[3*rr.y+2];
            const float* wr0 = s_wr + ((int)g0.w)*16 + c;
            const float w0 = E0a.x*wr0[0]  + E0a.y*wr0[16] + E0a.z*wr0[32] + E0a.w*wr0[48]
                           + E0b.x*wr0[64] + E0b.y*wr0[80] + E0b.z*wr0[96];
            gp_acc(A0, B0, g0, w0, m0,m1,m2,m3,m4,m5,m6,m7);
        }
    }

    __syncthreads();
    float* ag = &s_agg[nl*132 + c*8];
    *(float4*)(ag)     = make_float4(m0, m1, m2, m3);
    *(float4*)(ag + 4) = make_float4(m4, m5, m6, m7);
    __syncthreads();

    const int o = c;
    const float* A = &s_agg[nl*132];
    const float* H = &s_h[nl*132];

    float o0=0,o1=0,o2=0,o3=0,o4=0,o5=0,o6=0,o7=0;
    float q0=0,q1=0,q2=0,q3=0,q4=0,q5=0,q6=0,q7=0;
    #pragma unroll
    for (int cc = 0; cc < 16; ++cc) {
        const float wo = s_Wout[cc*16 + o];
        const float ws = s_Wsgp[cc*16 + o];
        const float* a  = A + cc*8;
        const float* hh = H + cc*8;
        o0 += a[0]*wo; o1 += a[1]*wo; o2 += a[2]*wo; o3 += a[3]*wo;
        o4 += a[4]*wo; o5 += a[5]*wo; o6 += a[6]*wo; o7 += a[7]*wo;
        q0 += hh[0]*ws; q1 += hh[1]*ws; q2 += hh[2]*ws; q3 += hh[3]*ws;
        q4 += hh[4]*ws; q5 += hh[5]*ws; q6 += hh[6]*ws; q7 += hh[7]*ws;
    }

    // res = out + gp(out, q), full Cl(3,0) Cayley product
    const float r0 = o0 + (o0*q0 + o1*q1 + o2*q2 + o3*q3 - o4*q4 - o5*q5 - o6*q6 - o7*q7);
    const float r1 = o1 + (o0*q1 + o1*q0 - o2*q4 - o3*q5 + o4*q2 + o5*q3 - o6*q7 - o7*q6);
    const float r2 = o2 + (o0*q2 + o1*q4 + o2*q0 - o3*q6 - o4*q1 + o5*q7 + o6*q3 + o7*q5);
    const float r3 = o3 + (o0*q3 + o1*q5 + o2*q6 + o3*q0 - o4*q7 - o5*q1 - o6*q2 - o7*q4);
    const float r4 = o4 + (o0*q4 + o1*q2 - o2*q1 + o3*q7 + o4*q0 - o5*q6 + o6*q5 + o7*q3);
    const float r5 = o5 + (o0*q5 + o1*q3 - o2*q7 - o3*q1 + o4*q6 + o5*q0 - o6*q4 - o7*q2);
    const float r6 = o6 + (o0*q6 + o1*q7 + o2*q3 - o3*q2 - o4*q5 + o5*q4 + o6*q0 + o7*q1);
    const float r7 = o7 + (o0*q7 + o1*q6 - o2*q5 + o3*q4 + o4*q3 - o5*q2 + o6*q1 + o7*q0);

    if (n < N) {
        float* op = out + (n*16 + o)*8;
        *(float4*)(op)     = make_float4(r0, r1, r2, r3);
        *(float4*)(op + 4) = make_float4(r4, r5, r6, r7);
    }
}

extern "C" void kernel_launch(void* const* d_in, const int* in_sizes, int n_in,
                              void* d_out, int out_size, void* d_ws, size_t ws_size,
                              hipStream_t stream) {
    const float* h    = (const float*)d_in[0];   // [N,16,8]
    const float* pos  = (const float*)d_in[1];   // [N,3]
    const int*   ei   = (const int*)d_in[2];     // [2,E]
    const float* Wrbf = (const float*)d_in[3];   // [32,16]
    const float* Wout = (const float*)d_in[4];   // [16,16]
    const float* Wsgp = (const float*)d_in[5];   // [16,16]
    float* out = (float*)d_out;

    const int N = in_sizes[0] / 128;
    const int E = in_sizes[2] / 2;

    // ws layout: cmp float4[3*cap] | rec2 int2[N*MAXDEG] | deg[N] | cnt[1]
    const size_t fixedBytes = (size_t)N * MAXDEG * sizeof(int2)
                            + (size_t)(N + 1) * sizeof(int);
    long long capLL = (long long)((ws_size - fixedBytes) / 48u);
    if (capLL > (long long)E + 1) capLL = (long long)E + 1;
    const int cap = (int)capLL;

    float4* cmp = (float4*)d_ws;
    int2* rec2  = (int2*)((char*)d_ws + (size_t)cap * 48u);
    int* deg    = (int*)(rec2 + (size_t)N * MAXDEG);
    int* cnt    = deg + N;

    hipMemsetAsync(deg, 0, (size_t)(N + 1) * sizeof(int), stream);

    const int eBlocks = (E + 255) / 256;
    k_fill_geom<<<eBlocks, 256, 0, stream>>>(pos, ei, deg, cnt, rec2, cmp, cap, E);

    const int gBlocks = (N + 15) / 16;
    k_gather_finalize<<<gBlocks, 256, 0, stream>>>(
        h, rec2, deg, cmp, Wrbf, Wout, Wsgp, out, N);
}

// Round 5
// 153.864 us; speedup vs baseline: 1.9345x; 1.9345x over previous
//
#include <hip/hip_runtime.h>

#define CUTOFF 5.0f
#define GAMMA 40.96f              // (32/5)^2
#define MU_STEP 0.16129032f       // 5/31 (RBF mu spacing)
#define PI_F 3.14159265358979f
#define MAXDEG 24                 // filtered degree ~Poisson(4.42); P(any node >=24) ~ 3e-6
#define TAB 2048                  // radial-weight table intervals
#define DSTEP (CUTOFF / (float)TAB)
#define TSCALE ((float)TAB / CUTOFF)

// ---------------------------------------------------------------------------
// R14: R11 structure (memset + fill + gather; bucketed edata; 16 thr/node,
// VGPR 60) with gather's serial RBF chain (2 exp + 14 ds_bpermute + clamp)
// replaced by a radial-weight lookup table:
//   w(c,d) = env(d) * (rbf(d) @ W_rbf)[c]  -- smooth in scalar d
// Table: float2 tabp[2048][16] = {f(d_i), f(d_i+DSTEP)} (256KB in ws), built
// by 128 extra blocks appended to the SAME fill dispatch (independent work,
// no sync needed; gather is the next dispatch). Exact 32-term RBF sum in the
// table (R11 used a 7-term window); lerp error ~6e-5 relative.
// R13 lessons applied: NO single-address atomic counter (153us serialization);
// edge data stays bucketed/sequential.
// ws: tabp 256KB | edata float4[N*24] 19.2MB | deg[N] | rec[N*24] = 24.5MB.
// ---------------------------------------------------------------------------

__global__ __launch_bounds__(256) void k_fill_geom(
    const float* __restrict__ pos, const int* __restrict__ ei,
    const float* __restrict__ Wrbf,
    int* __restrict__ deg, int* __restrict__ rec,
    float4* __restrict__ edata, float2* __restrict__ tabp,
    int E, int eBlocks)
{
    if (blockIdx.x >= eBlocks) {
        // ---- radial-weight table builder: 128 blocks, 32768 (interval,chan)
        const int gid = (blockIdx.x - eBlocks) * 256 + threadIdx.x;
        const int i = gid >> 4;          // interval 0..2047
        const int c = gid & 15;          // channel
        const float d0 = (float)i * DSTEP;
        const float d1 = d0 + DSTEP;
        float acc0 = 0.0f, acc1 = 0.0f;
        #pragma unroll
        for (int k = 0; k < 32; ++k) {
            const float w  = Wrbf[k*16 + c];
            const float x0 = d0 - MU_STEP * (float)k;
            const float x1 = d1 - MU_STEP * (float)k;
            acc0 += __expf(-GAMMA * x0 * x0) * w;
            acc1 += __expf(-GAMMA * x1 * x1) * w;
        }
        const float env0 = 0.5f * (__cosf(PI_F * d0 * (1.0f/CUTOFF)) + 1.0f);
        const float env1 = 0.5f * (__cosf(PI_F * d1 * (1.0f/CUTOFF)) + 1.0f);
        tabp[gid] = make_float2(acc0 * env0, acc1 * env1);
        return;
    }

    // ---- edge bucket fill (R11 verbatim, minus env fold -- env is in table)
    const int e = blockIdx.x * 256 + threadIdx.x;
    if (e >= E) return;
    const int src = ei[e], dst = ei[E + e];
    const float dx = pos[dst*3+0] - pos[src*3+0];
    const float dy = pos[dst*3+1] - pos[src*3+1];
    const float dz = pos[dst*3+2] - pos[src*3+2];
    const float d = sqrtf(dx*dx + dy*dy + dz*dz + 1e-12f);
    if (d < CUTOFF) {
        const int slot = atomicAdd(&deg[dst], 1);
        if (slot < MAXDEG) {               // guard: never taken in practice
            const float inv = 1.0f / d;
            rec[dst*MAXDEG + slot] = src;
            edata[(size_t)dst*MAXDEG + slot] = make_float4(dx*inv, dy*inv, dz*inv, d);
        }
    }
}

__global__ __launch_bounds__(256) void k_gather_finalize(
    const float* __restrict__ h,
    const int* __restrict__ rec, const int* __restrict__ deg,
    const float4* __restrict__ edata, const float2* __restrict__ tabp,
    const float* __restrict__ Wout, const float* __restrict__ Wsgp,
    float* __restrict__ out, int N)
{
    __shared__ float s_Wout[256];
    __shared__ float s_Wsgp[256];
    __shared__ float s_agg[16*132];
    __shared__ float s_h[16*132];

    const int t  = threadIdx.x;
    const int nl = t >> 4;
    const int c  = t & 15;
    const long long nodeBase = (long long)blockIdx.x * 16;
    const long long n = nodeBase + nl;

    s_Wout[t] = Wout[t];
    s_Wsgp[t] = Wsgp[t];

    for (int idx = t; idx < 512; idx += 256) {
        int nn = idx >> 5;
        int r  = idx & 31;
        long long node = nodeBase + nn;
        float4 vh = make_float4(0,0,0,0);
        if (node < N) vh = *(const float4*)(h + node*128 + (long long)r*4);
        *(float4*)(&s_h[nn*132 + r*4]) = vh;
    }
    __syncthreads();

    float m0=0,m1=0,m2=0,m3=0,m4=0,m5=0,m6=0,m7=0;
    if (n < N) {
        const int start = (int)n * MAXDEG;
        const int dg    = min(deg[n], MAXDEG);
        for (int base = 0; base < dg; base += 2) {
            const int i1ok = (base + 1 < dg) ? 1 : 0;
            const int s0 = rec[start + base];
            const int s1 = rec[start + base + i1ok];   // repeats s0 when odd tail
            const float4 g0 = edata[start + base];
            const float4 g1 = edata[start + base + i1ok];

            // hoist h loads: 2 independent 32B chains in flight during w math
            const float4* hp0 = (const float4*)(h + (((long long)s0*16 + c) << 3));
            const float4* hp1 = (const float4*)(h + (((long long)s1*16 + c) << 3));
            const float4 A0 = hp0[0], B0 = hp0[1];
            const float4 A1 = hp1[0], B1 = hp1[1];

            // radial weight via table lerp (env + full 32-term RBF folded in);
            // depends only on the early edata load -- off the h critical path
            const float u0 = g0.w * TSCALE;
            const float u1 = g1.w * TSCALE;
            int it0 = (int)u0; it0 = min(it0, TAB - 1);
            int it1 = (int)u1; it1 = min(it1, TAB - 1);
            const float fr0 = u0 - (float)it0;
            const float fr1 = u1 - (float)it1;
            const float2 tp0 = tabp[it0*16 + c];
            const float2 tp1 = tabp[it1*16 + c];
            const float w0 = tp0.x + fr0 * (tp0.y - tp0.x);
            float       w1 = tp1.x + fr1 * (tp1.y - tp1.x);
            w1 *= (float)i1ok;

            // gp(a, v), v grade-1 unit rel vector;
            // blades: 0:1 1:e1 2:e2 3:e3 4:e12 5:e13 6:e23 7:e123
            m0 += (A0.y*g0.x + A0.z*g0.y + A0.w*g0.z)*w0 + (A1.y*g1.x + A1.z*g1.y + A1.w*g1.z)*w1;
            m1 += (A0.x*g0.x + B0.x*g0.y + B0.y*g0.z)*w0 + (A1.x*g1.x + B1.x*g1.y + B1.y*g1.z)*w1;
            m2 += (A0.x*g0.y - B0.x*g0.x + B0.z*g0.z)*w0 + (A1.x*g1.y - B1.x*g1.x + B1.z*g1.z)*w1;
            m3 += (A0.x*g0.z - B0.y*g0.x - B0.z*g0.y)*w0 + (A1.x*g1.z - B1.y*g1.x - B1.z*g1.y)*w1;
            m4 += (A0.y*g0.y - A0.z*g0.x + B0.w*g0.z)*w0 + (A1.y*g1.y - A1.z*g1.x + B1.w*g1.z)*w1;
            m5 += (A0.y*g0.z - A0.w*g0.x - B0.w*g0.y)*w0 + (A1.y*g1.z - A1.w*g1.x - B1.w*g1.y)*w1;
            m6 += (A0.z*g0.z - A0.w*g0.y + B0.w*g0.x)*w0 + (A1.z*g1.z - A1.w*g1.y + B1.w*g1.x)*w1;
            m7 += (B0.z*g0.x - B0.y*g0.y + B0.x*g0.z)*w0 + (B1.z*g1.x - B1.y*g1.y + B1.x*g1.z)*w1;
        }
    }

    __syncthreads();
    float* ag = &s_agg[nl*132 + c*8];
    *(float4*)(ag)     = make_float4(m0, m1, m2, m3);
    *(float4*)(ag + 4) = make_float4(m4, m5, m6, m7);
    __syncthreads();

    const int o = c;
    const float* A = &s_agg[nl*132];
    const float* H = &s_h[nl*132];

    float o0=0,o1=0,o2=0,o3=0,o4=0,o5=0,o6=0,o7=0;
    float q0=0,q1=0,q2=0,q3=0,q4=0,q5=0,q6=0,q7=0;
    #pragma unroll
    for (int cc = 0; cc < 16; ++cc) {
        const float wo = s_Wout[cc*16 + o];
        const float ws = s_Wsgp[cc*16 + o];
        const float* a  = A + cc*8;
        const float* hh = H + cc*8;
        o0 += a[0]*wo; o1 += a[1]*wo; o2 += a[2]*wo; o3 += a[3]*wo;
        o4 += a[4]*wo; o5 += a[5]*wo; o6 += a[6]*wo; o7 += a[7]*wo;
        q0 += hh[0]*ws; q1 += hh[1]*ws; q2 += hh[2]*ws; q3 += hh[3]*ws;
        q4 += hh[4]*ws; q5 += hh[5]*ws; q6 += hh[6]*ws; q7 += hh[7]*ws;
    }

    // res = out + gp(out, q), full Cl(3,0) Cayley product
    const float r0 = o0 + (o0*q0 + o1*q1 + o2*q2 + o3*q3 - o4*q4 - o5*q5 - o6*q6 - o7*q7);
    const float r1 = o1 + (o0*q1 + o1*q0 - o2*q4 - o3*q5 + o4*q2 + o5*q3 - o6*q7 - o7*q6);
    const float r2 = o2 + (o0*q2 + o1*q4 + o2*q0 - o3*q6 - o4*q1 + o5*q7 + o6*q3 + o7*q5);
    const float r3 = o3 + (o0*q3 + o1*q5 + o2*q6 + o3*q0 - o4*q7 - o5*q1 - o6*q2 - o7*q4);
    const float r4 = o4 + (o0*q4 + o1*q2 - o2*q1 + o3*q7 + o4*q0 - o5*q6 + o6*q5 + o7*q3);
    const float r5 = o5 + (o0*q5 + o1*q3 - o2*q7 - o3*q1 + o4*q6 + o5*q0 - o6*q4 - o7*q2);
    const float r6 = o6 + (o0*q6 + o1*q7 + o2*q3 - o3*q2 - o4*q5 + o5*q4 + o6*q0 + o7*q1);
    const float r7 = o7 + (o0*q7 + o1*q6 - o2*q5 + o3*q4 + o4*q3 - o5*q2 + o6*q1 + o7*q0);

    if (n < N) {
        float* op = out + (n*16 + o)*8;
        *(float4*)(op)     = make_float4(r0, r1, r2, r3);
        *(float4*)(op + 4) = make_float4(r4, r5, r6, r7);
    }
}

extern "C" void kernel_launch(void* const* d_in, const int* in_sizes, int n_in,
                              void* d_out, int out_size, void* d_ws, size_t ws_size,
                              hipStream_t stream) {
    const float* h    = (const float*)d_in[0];   // [N,16,8]
    const float* pos  = (const float*)d_in[1];   // [N,3]
    const int*   ei   = (const int*)d_in[2];     // [2,E]
    const float* Wrbf = (const float*)d_in[3];   // [32,16]
    const float* Wout = (const float*)d_in[4];   // [16,16]
    const float* Wsgp = (const float*)d_in[5];   // [16,16]
    float* out = (float*)d_out;

    const int N = in_sizes[0] / 128;
    const int E = in_sizes[2] / 2;

    // ws layout: tabp float2[TAB*16] (256KB) | edata float4[N*MAXDEG] (19.2MB)
    //            | deg[N] | rec[N*MAXDEG] (4.8MB)  -- total ~24.5MB
    float2* tabp  = (float2*)d_ws;
    float4* edata = (float4*)(tabp + (size_t)TAB * 16);
    int* deg = (int*)(edata + (size_t)N * MAXDEG);
    int* rec = deg + N;

    hipMemsetAsync(deg, 0, (size_t)N * sizeof(int), stream);

    const int eBlocks = (E + 255) / 256;
    const int tBlocks = (TAB * 16) / 256;        // 128 table-builder blocks
    k_fill_geom<<<eBlocks + tBlocks, 256, 0, stream>>>(
        pos, ei, Wrbf, deg, rec, edata, tabp, E, eBlocks);

    const int gBlocks = (N + 15) / 16;
    k_gather_finalize<<<gBlocks, 256, 0, stream>>>(
        h, rec, deg, edata, tabp, Wout, Wsgp, out, N);
}